// Round 25
// baseline (580.238 us; speedup 1.0000x reference)
//
#include <hip/hip_runtime.h>
#include <cstdint>
#include <cstddef>

#define L_SEQ 4096
#define H_DIM 256
#define N_MODES 64
#define BATCH 16
#define QCH 128
#define NCHUNK 32
#define LPAD (L_SEQ + 8)

typedef __attribute__((ext_vector_type(8))) short short8v;
typedef __attribute__((ext_vector_type(16))) float f32x16;

#define MFMA32(a, b, c) __builtin_amdgcn_mfma_f32_32x32x16_bf16((a), (b), (c), 0, 0, 0)

__device__ __forceinline__ unsigned short f2bf(float f) {
    unsigned u = __float_as_uint(f);
    u = u + 0x7fff + ((u >> 16) & 1);
    return (unsigned short)(u >> 16);
}
__device__ __forceinline__ float bf2f(unsigned short h) {
    return __uint_as_float(((unsigned)h) << 16);
}
// wave-local LDS ordering fence (rule #18): orders this wave's DS ops without
// a block-wide barrier. Used where the LDS tile is wave-private.
__device__ __forceinline__ void wave_lds_fence() {
    asm volatile("s_waitcnt lgkmcnt(0)" ::: "memory");
    __builtin_amdgcn_sched_barrier(0);
}
// tanh-GELU via sigmoid identity: 0.5*y*(1+tanh(z)) = y*sigmoid(2z), fast exp
__device__ __forceinline__ float fast_gelu(float y) {
    float t = fmaf(0.044715f * y * y, y, y);
    return y / (1.f + __expf(-1.5957691f * t));
}
__device__ __forceinline__ float fast_sigmoid_mul(float z1, float z2) {
    return z1 / (1.f + __expf(-z2));
}

// packed B-fragment position for 32x32x16 bf16: entry (k, col)
__device__ __forceinline__ int bpos(int k, int col) {
    return ((col >> 5) * 8 + (k >> 4)) * 512 + ((col & 31) + 32 * ((k >> 3) & 1)) * 8 + (k & 7);
}
__device__ __forceinline__ void whi(unsigned short* M, int k, int col, float v) {
    M[bpos(k, col)] = f2bf(v);
}

// ---------------------------------------------------------------------------
// Per-layer S4D matrices (hi-plane only) + fused Toeplitz fill, DIRECT FORM:
// w^d = exp(dr*d)*(cos(di*d), sin(di*d)) -- every (d,n) entry independent.
// Grid 256 (one block per h); d-loop strided over the 4 waves.
// ---------------------------------------------------------------------------
__global__ __launch_bounds__(256) void mats_gen(
    const float* __restrict__ log_dt, const float* __restrict__ A_re_log,
    const float* __restrict__ A_im, const float* __restrict__ C_re,
    const float* __restrict__ C_im, const float* __restrict__ Dv, int layer,
    unsigned short* __restrict__ Vpk, unsigned short* __restrict__ Epk,
    unsigned short* __restrict__ Tpk, float* __restrict__ wqbuf)
{
    __shared__ float Kl[128];
    const int wv = threadIdx.x >> 6, n = threadIdx.x & 63;
    const int h = blockIdx.x;
    const int idx = (layer * H_DIM + h) * N_MODES + n;
    float dt = expf(log_dt[layer * H_DIM + h]);
    float Ar = -expf(A_re_log[idx]);
    float Ai = A_im[idx];
    float dr = Ar * dt, di = Ai * dt;
    float Cr = C_re[idx], Ci = C_im[idx];
    // w = exp(dr)*(cos di, sin di); c2 = 2*C*(w-1)/A
    float er1 = expf(dr);
    float wr = er1 * cosf(di), wi = er1 * sinf(di);
    float nr = wr - 1.f, ni = wi;
    float pr_ = Cr * nr - Ci * ni;
    float pi_ = Cr * ni + Ci * nr;
    float inv = 1.f / (Ar * Ar + Ai * Ai);
    float c2r = 2.f * (pr_ * Ar + pi_ * Ai) * inv;
    float c2i = 2.f * (pi_ * Ar - pr_ * Ai) * inv;
    float Dh = Dv[layer * H_DIM + h];
    unsigned short* Vh = Vpk + h * 32768;
    unsigned short* Eh = Epk + h * 32768;

    for (int d = wv; d <= QCH; d += 4) {
        float fd = (float)d;
        float erd = expf(dr * fd);
        float pr = erd * cosf(di * fd);     // Re(w^d)
        float pi = erd * sinf(di * fd);     // Im(w^d)
        float qr = c2r * pr - c2i * pi;     // c2 * w^d
        float qi = c2r * pi + c2i * pr;
        if (d <= QCH - 1) {
            int t = QCH - 1 - d;
            whi(Vh, t, 2 * n, pr);
            whi(Vh, t, 2 * n + 1, pi);
            float s = qr;                   // K[d] = sum_n Re(c2 w^d) (+D at 0)
            #pragma unroll
            for (int st = 1; st < 64; st <<= 1) s += __shfl_xor(s, st);
            if (n == 0) Kl[d] = s + (d == 0 ? Dh : 0.f);
        }
        if (d >= 1) {
            int t = d - 1;
            whi(Eh, 2 * n, t, qr);
            whi(Eh, 2 * n + 1, t, -qi);
        }
        if (d == QCH) {
            wqbuf[(h * 64 + n) * 2 + 0] = pr;   // wQ = w^128
            wqbuf[(h * 64 + n) * 2 + 1] = pi;
        }
    }
    __syncthreads();
    // Toeplitz fill (hi only): B[j][t] = K[t-j]; 32 groups split over 4 waves
    unsigned short* Th = Tpk + h * 32768;
    for (int g = wv; g < 32; g += 4) {
        int nt = g >> 3, ks = g & 7;
        int col = nt * 32 + (n & 31);
        int k0 = ks * 16 + (n >> 5) * 8;
        union { unsigned short s[8]; uint4 v; } hi;
        #pragma unroll
        for (int j = 0; j < 8; ++j) {
            int d = col - (k0 + j);
            hi.s[j] = f2bf((d >= 0) ? Kl[d] : 0.f);
        }
        *(uint4*)(Th + (nt * 8 + ks) * 512 + n * 8) = hi.v;
    }
}

// ---------------------------------------------------------------------------
// Conv weight pack (BN-folded) into MFMA B-frag order per shift k, + bias.
// ---------------------------------------------------------------------------
template<int CI, int K, int CO>
__global__ __launch_bounds__(256) void pack_conv(
    const float* __restrict__ wg, const float* __restrict__ g,
    const float* __restrict__ v, const float* __restrict__ cb,
    const float* __restrict__ m, const float* __restrict__ bb,
    unsigned short* __restrict__ Wc, float* __restrict__ Bs)
{
    constexpr int NT = CO / 32, KS = CI / 16;
    int t = blockIdx.x * 256 + threadIdx.x;
    if (t < CO) Bs[t] = (cb[t] - m[t]) * g[t] * rsqrtf(v[t] + 1e-5f) + bb[t];
    if (t >= K * NT * KS * 64) return;
    int lane = t & 63;
    int rest = t >> 6;
    int ks = rest % KS;
    int nt = (rest / KS) % NT;
    int k = rest / (KS * NT);
    int co = nt * 32 + (lane & 31);
    int ci0 = ks * 16 + (lane >> 5) * 8;
    float s = g[co] * rsqrtf(v[co] + 1e-5f);
    union { unsigned short s_[8]; uint4 v_; } hi;
    #pragma unroll
    for (int j = 0; j < 8; ++j) {
        float f = wg[((size_t)co * CI + ci0 + j) * K + k] * s;
        hi.s_[j] = f2bf(f);
    }
    size_t base = ((size_t)(k * NT + nt) * KS + ks) * 512 + lane * 8;
    *(uint4*)(Wc + base) = hi.v_;
}

// ---------------------------------------------------------------------------
// Conv1 (CI=1): validated VALU version.
// ---------------------------------------------------------------------------
template<int CI, int K>
__global__ __launch_bounds__(256) void conv_bn_relu_f(
    const float* __restrict__ in, float* __restrict__ out,
    const float* __restrict__ wg, const float* __restrict__ cb,
    const float* __restrict__ g, const float* __restrict__ bb,
    const float* __restrict__ m, const float* __restrict__ v, int CO)
{
    const int wv = threadIdx.x >> 6, lane = threadIdx.x & 63;
    const int b = blockIdx.z;
    const int co0 = __builtin_amdgcn_readfirstlane(blockIdx.y * 32 + wv * 8);
    const int l = blockIdx.x * 256 + lane * 4;
    const int OFF = K / 2;
    float acc[8][4] = {};
    const float* inb = in + (size_t)b * CI * L_SEQ;
    for (int ci = 0; ci < CI; ++ci) {
        const float* row = inb + (size_t)ci * L_SEQ;
        float win[12];
        #pragma unroll
        for (int d = 0; d < 12; ++d) {
            int li = l - 4 + d;
            win[d] = (li >= 0 && li < L_SEQ) ? row[li] : 0.f;
        }
        #pragma unroll
        for (int cc = 0; cc < 8; ++cc) {
            #pragma unroll
            for (int k = 0; k < K; ++k) {
                float wk = wg[((size_t)(co0 + cc) * CI + ci) * K + k];
                #pragma unroll
                for (int j = 0; j < 4; ++j)
                    acc[cc][j] = fmaf(win[4 + j + k - OFF], wk, acc[cc][j]);
            }
        }
    }
    #pragma unroll
    for (int cc = 0; cc < 8; ++cc) {
        int co = co0 + cc;
        float s = g[co] * rsqrtf(v[co] + 1e-5f);
        float sh = (cb[co] - m[co]) * s + bb[co];
        float* orow = out + ((size_t)b * CO + co) * LPAD + 4;
        float4 o4;
        o4.x = fmaxf(fmaf(acc[cc][0], s, sh), 0.f);
        o4.y = fmaxf(fmaf(acc[cc][1], s, sh), 0.f);
        o4.z = fmaxf(fmaf(acc[cc][2], s, sh), 0.f);
        o4.w = fmaxf(fmaf(acc[cc][3], s, sh), 0.f);
        *(float4*)(orow + l) = o4;
        if (blockIdx.x == 0 && lane == 0)
            *(float4*)(orow - 4) = make_float4(0.f, 0.f, 0.f, 0.f);
        if (blockIdx.x == gridDim.x - 1 && lane == 63)
            *(float4*)(orow + L_SEQ) = make_float4(0.f, 0.f, 0.f, 0.f);
    }
}

// ---------------------------------------------------------------------------
// Conv via MFMA implicit GEMM, hi-plane only (r13 numerics: A is bf16-rounded,
// lo corrections below noise floor). OBF: store output as bf16 [B][CO][L].
// ---------------------------------------------------------------------------
template<int CI, int K, int CO, bool POUT, bool OBF>
__global__ __launch_bounds__(256) void conv_mfma(
    const float* __restrict__ in, void* __restrict__ outv,
    const unsigned short* __restrict__ Wc, const float* __restrict__ Bs)
{
    constexpr int NT = CO / 32, KS = CI / 16, OBS = NT / 4, OFF = K / 2;
    __shared__ __align__(16) unsigned short A0[40 * CI];
    __shared__ __align__(16) char vtraw[32 * (CO + 8) * (OBF ? 2 : 4)];
    const int b = blockIdx.y, l0 = blockIdx.x * 32;
    const int wv = threadIdx.x >> 6, lane = threadIdx.x & 63;
    const float* inb = in + (size_t)b * CI * LPAD + l0;
    for (int e = threadIdx.x; e < CI * 10; e += 256) {
        int ci = e / 10, f4 = e - ci * 10;
        float4 q = *(const float4*)(inb + (size_t)ci * LPAD + f4 * 4);
        #pragma unroll
        for (int j = 0; j < 4; ++j) {
            int row = f4 * 4 + j;
            int bo = ((row * CI + ci) * 2) ^ ((row & 7) << 4);
            *(unsigned short*)((char*)A0 + bo) = f2bf((&q.x)[j]);
        }
    }
    __syncthreads();
    f32x16 acc0 = {}, acc1 = {};
    #pragma unroll
    for (int k = 0; k < K; ++k) {
        #pragma unroll
        for (int ks = 0; ks < KS; ++ks) {
            int row = (lane & 31) + 4 + k - OFF;
            int abyte = ((row * CI + ks * 16 + (lane >> 5) * 8) * 2) ^ ((row & 7) << 4);
            short8v ah = *(const short8v*)((const char*)A0 + abyte);
            {
                const unsigned short* wb = Wc + ((size_t)(k * NT + wv * OBS) * KS + ks) * 512 + lane * 8;
                short8v bh = *(const short8v*)wb;
                acc0 = MFMA32(ah, bh, acc0);
            }
            if constexpr (OBS == 2) {
                const unsigned short* wb = Wc + ((size_t)(k * NT + wv * OBS + 1) * KS + ks) * 512 + lane * 8;
                short8v bh = *(const short8v*)wb;
                acc1 = MFMA32(ah, bh, acc1);
            }
        }
    }
    __syncthreads();   // A-tile reads done before vtraw repurpose ordering
    if constexpr (OBF) {
        unsigned short* vtb = (unsigned short*)vtraw;   // [32][CO+8] bf16
        int co = (wv * OBS) * 32 + (lane & 31);
        float bs = Bs[co];
        #pragma unroll
        for (int r = 0; r < 16; ++r) {
            int lr = (r & 3) + 8 * (r >> 2) + 4 * (lane >> 5);
            vtb[lr * (CO + 8) + co] = f2bf(fmaxf(acc0[r] + bs, 0.f));
        }
        if constexpr (OBS == 2) {
            int co1 = co + 32;
            float bs1 = Bs[co1];
            #pragma unroll
            for (int r = 0; r < 16; ++r) {
                int lr = (r & 3) + 8 * (r >> 2) + 4 * (lane >> 5);
                vtb[lr * (CO + 8) + co1] = f2bf(fmaxf(acc1[r] + bs1, 0.f));
            }
        }
        __syncthreads();
        unsigned short* orow = (unsigned short*)outv
            + ((size_t)b * CO + threadIdx.x) * L_SEQ + l0;
        #pragma unroll
        for (int u8 = 0; u8 < 4; ++u8) {
            union { unsigned short s[8]; uint4 v; } pk;
            #pragma unroll
            for (int j = 0; j < 8; ++j)
                pk.s[j] = vtb[(u8 * 8 + j) * (CO + 8) + threadIdx.x];
            *(uint4*)(orow + u8 * 8) = pk.v;
        }
    } else {
        float* vt = (float*)vtraw;                      // [32][CO+8] fp32
        {
            int co = (wv * OBS) * 32 + (lane & 31);
            float bs = Bs[co];
            #pragma unroll
            for (int r = 0; r < 16; ++r) {
                int lr = (r & 3) + 8 * (r >> 2) + 4 * (lane >> 5);
                vt[lr * (CO + 8) + co] = fmaxf(acc0[r] + bs, 0.f);
            }
            if constexpr (OBS == 2) {
                int co1 = co + 32;
                float bs1 = Bs[co1];
                #pragma unroll
                for (int r = 0; r < 16; ++r) {
                    int lr = (r & 3) + 8 * (r >> 2) + 4 * (lane >> 5);
                    vt[lr * (CO + 8) + co1] = fmaxf(acc1[r] + bs1, 0.f);
                }
            }
        }
        __syncthreads();
        float* out = (float*)outv;
        int co = threadIdx.x & 127, lh = threadIdx.x >> 7;
        float* rowb = out + ((size_t)b * CO + co) * LPAD;
        float* orow = rowb + 4 + l0 + lh * 16;
        #pragma unroll
        for (int u4 = 0; u4 < 4; ++u4) {
            float4 o;
            o.x = vt[(lh * 16 + u4 * 4 + 0) * (CO + 8) + co];
            o.y = vt[(lh * 16 + u4 * 4 + 1) * (CO + 8) + co];
            o.z = vt[(lh * 16 + u4 * 4 + 2) * (CO + 8) + co];
            o.w = vt[(lh * 16 + u4 * 4 + 3) * (CO + 8) + co];
            *(float4*)(orow + u4 * 4) = o;
        }
        if (blockIdx.x == 0 && lh == 0)
            *(float4*)(rowb) = make_float4(0.f, 0.f, 0.f, 0.f);
        if (blockIdx.x == gridDim.x - 1 && lh == 1)
            *(float4*)(rowb + 4 + L_SEQ) = make_float4(0.f, 0.f, 0.f, 0.f);
    }
}

// ---------------------------------------------------------------------------
// Fused S4D core v10: register-bracket diet. Phases A/C split into two
// nt-halves (2 accs live -> 32 AGPR, was 64); uh streamed from global (L2-hot)
// instead of 32 persistent VGPRs; phase-B prefix in two 16-chunk halves
// (32 regs, was 64). Target: VGPR+AGPR <= 128 -> 4 waves/SIMD (was 2).
// Arithmetic identical to v9.
// ---------------------------------------------------------------------------
__global__ __launch_bounds__(256) void s4d_fused(
    const unsigned short* __restrict__ u,    // [B][256][L] bf16
    const unsigned short* __restrict__ Vpk,
    const unsigned short* __restrict__ Epk,
    const unsigned short* __restrict__ Tpk,
    const float* __restrict__ wqbuf,
    unsigned short* __restrict__ ybf)        // [B][H][L] bf16
{
    __shared__ __align__(16) unsigned short Sb[4][4096];
    const int h = blockIdx.x;
    const int wv = threadIdx.x >> 6, lane = threadIdx.x & 63;
    const int b = blockIdx.y * 4 + wv;
    const unsigned short* urow = u + ((size_t)b * H_DIM + h) * L_SEQ;
    const int c = lane & 31;
    const int khalf = (lane >> 5) * 8;
    char* Sw = (char*)Sb[wv];

    // ---- Phase A: S = x @ V, two nt-halves (32 AGPR peak) ----
    #pragma unroll 1
    for (int half = 0; half < 2; ++half) {
        f32x16 acc0 = {}, acc1 = {};
        const unsigned short* Vh = Vpk + h * 32768 + half * 8192;
        #pragma unroll
        for (int ks = 0; ks < 8; ++ks) {
            short8v uh = *(const short8v*)(urow + c * 128 + ks * 16 + khalf);
            const unsigned short* vb = Vh + ks * 512 + lane * 8;
            short8v b0h = *(const short8v*)(vb);
            short8v b1h = *(const short8v*)(vb + 4096);
            acc0 = MFMA32(uh, b0h, acc0);
            acc1 = MFMA32(uh, b1h, acc1);
        }
        #pragma unroll
        for (int nt2 = 0; nt2 < 2; ++nt2) {
            const f32x16& a = nt2 ? acc1 : acc0;
            int col = (half * 2 + nt2) * 32 + c;
            #pragma unroll
            for (int r = 0; r < 16; ++r) {
                int cc = (r & 3) + 8 * (r >> 2) + 4 * (lane >> 5);
                int boff = (cc * 256 + col * 2) ^ ((cc & 15) << 4);
                *(unsigned short*)(Sw + boff) = f2bf(a[r]);
            }
        }
    }
    wave_lds_fence();   // scatter ordered before prefix reads (wave-private tile)

    // ---- Phase B: chunk-prefix over wQ, two 16-chunk halves (32 regs) ----
    {
        const float2 wq = *(const float2*)(wqbuf + ((size_t)h * 64 + lane) * 2);
        float Pr = 0.f, Pi = 0.f;
        #pragma unroll 1
        for (int hb = 0; hb < 2; ++hb) {
            float sr[16], si[16];
            #pragma unroll
            for (int c2 = 0; c2 < 16; ++c2) {
                int cc = hb * 16 + c2;
                int boff = (cc * 256 + lane * 4) ^ ((cc & 15) << 4);
                sr[c2] = bf2f(*(const unsigned short*)(Sw + boff));
                si[c2] = bf2f(*(const unsigned short*)(Sw + boff + 2));
            }
            #pragma unroll
            for (int c2 = 0; c2 < 16; ++c2) {
                int cc = hb * 16 + c2;
                int boff = (cc * 256 + lane * 4) ^ ((cc & 15) << 4);
                *(unsigned short*)(Sw + boff) = f2bf(Pr);
                *(unsigned short*)(Sw + boff + 2) = f2bf(Pi);
                float npr = fmaf(wq.x, Pr, fmaf(-wq.y, Pi, sr[c2]));
                float npi = fmaf(wq.x, Pi, fmaf(wq.y, Pr, si[c2]));
                Pr = npr; Pi = npi;
            }
        }
    }
    wave_lds_fence();   // P writes ordered before phase-C vector reads

    // ---- Phase C: y = P @ E + x @ T, two nt-halves (32 AGPR peak) ----
    const int swzc = (c & 15) << 4;
    unsigned short* yrow = ybf + ((size_t)b * H_DIM + h) * L_SEQ;
    #pragma unroll 1
    for (int half = 0; half < 2; ++half) {
        f32x16 acc0 = {}, acc1 = {};
        const unsigned short* Eh = Epk + h * 32768 + half * 8192;
        const unsigned short* Th = Tpk + h * 32768 + half * 8192;
        #pragma unroll
        for (int ks = 0; ks < 8; ++ks) {
            int boff = (c * 256 + (ks * 16 + khalf) * 2) ^ swzc;
            short8v ah = *(const short8v*)(Sw + boff);
            short8v uh = *(const short8v*)(urow + c * 128 + ks * 16 + khalf);
            const unsigned short* eb = Eh + ks * 512 + lane * 8;
            const unsigned short* tb = Th + ks * 512 + lane * 8;
            short8v e0 = *(const short8v*)(eb);
            short8v e1 = *(const short8v*)(eb + 4096);
            short8v t0 = *(const short8v*)(tb);
            short8v t1 = *(const short8v*)(tb + 4096);
            acc0 = MFMA32(ah, e0, acc0);
            acc1 = MFMA32(ah, e1, acc1);
            acc0 = MFMA32(uh, t0, acc0);
            acc1 = MFMA32(uh, t1, acc1);
        }
        #pragma unroll
        for (int nt2 = 0; nt2 < 2; ++nt2) {
            const f32x16& a = nt2 ? acc1 : acc0;
            int t = (half * 2 + nt2) * 32 + c;
            #pragma unroll
            for (int r = 0; r < 16; ++r) {
                int cc = (r & 3) + 8 * (r >> 2) + 4 * (lane >> 5);
                yrow[cc * QCH + t] = f2bf(fast_gelu(a[r]));
            }
        }
    }
}

// ---------------------------------------------------------------------------
// W -> packed MFMA B-fragment order (GLU linear).
// ---------------------------------------------------------------------------
__global__ __launch_bounds__(256) void precompute_wpk(
    const float* __restrict__ W, unsigned short* __restrict__ Wpk)
{
    int t = blockIdx.x * 256 + threadIdx.x;
    if (t >= 4 * 16 * 16 * 64) return;
    int lane = t & 63;
    int kk = (t >> 6) & 15;
    int ob = (t >> 10) & 15;
    int layer = t >> 14;
    int o = ob * 32 + (lane & 31);
    int k0 = kk * 16 + (lane >> 5) * 8;
    const float* src = W + ((size_t)layer * 512 + o) * H_DIM + k0;
    union { unsigned short s[8]; uint4 v; } hi;
    #pragma unroll
    for (int j = 0; j < 8; ++j) hi.s[j] = f2bf(src[j]);
    size_t base = (size_t)layer * 262144 + ((size_t)((ob * 16 + kk) * 64 + lane) * 8);
    *(uint4*)(Wpk + base) = hi.v;
}

// ---------------------------------------------------------------------------
// Output linear (H->2H) MFMA + GLU + residual + LayerNorm, fused.
// v4 (validated r19/r21 best): 512-thread blocks, wave-group per tile.
// LAST: accumulate per-(b,h) sums into meanb via atomicAdd (pool fusion).
// ---------------------------------------------------------------------------
template<bool LAST>
__global__ __launch_bounds__(512) void linear_glu_ln(
    const unsigned short* __restrict__ ybf,
    const unsigned short* __restrict__ Wpk,
    const float* __restrict__ bias,
    const float* __restrict__ lg, const float* __restrict__ lb,
    unsigned short* __restrict__ xbf, float* __restrict__ meanb)
{
    __shared__ __align__(16) unsigned short Sm[2][8448];
    const int lane = threadIdx.x & 63;
    const int t = threadIdx.x >> 8;          // tile group (0 or 1)
    const int tid_t = threadIdx.x & 255;     // thread id within tile group
    const int wv4 = (threadIdx.x >> 6) & 3;  // wave within tile group
    const int b = blockIdx.y;
    const int l0 = blockIdx.x * 64;
    const int lt0 = l0 + t * 32;
    unsigned short* Smt = Sm[t];

    {
        const unsigned short* ybase = ybf + (size_t)b * H_DIM * L_SEQ + lt0;
        #pragma unroll
        for (int p = 0; p < 4; ++p) {
            int e = tid_t + p * 256;
            int hh = e >> 2, c4 = e & 3;
            union { uint4 v; unsigned short s[8]; } qv;
            qv.v = *(const uint4*)(ybase + (size_t)hh * L_SEQ + c4 * 8);
            #pragma unroll
            for (int j = 0; j < 8; ++j) {
                int lloc = c4 * 8 + j;
                int byteoff = (lloc << 9) + hh * 2;
                byteoff ^= ((lloc & 15) << 4);
                *(unsigned short*)((char*)Smt + byteoff) = qv.s[j];
            }
        }
    }
    __syncthreads();

    const int ob0 = 2 * wv4, ob1 = 2 * wv4 + 1;
    const int r = lane & 31;
    const float4 g4 = *(const float4*)(lg + lane * 4);
    const float4 b4 = *(const float4*)(lb + lane * 4);
    float msum = 0.f;

    f32x16 acc0 = {}, acc1 = {}, acc2 = {}, acc3 = {};
    #pragma unroll 4
    for (int kk = 0; kk < 16; ++kk) {
        int abyte = (r << 9) | (kk * 32 + (lane >> 5) * 16);
        abyte ^= ((r & 15) << 4);
        short8v a = *(const short8v*)((char*)Smt + abyte);
        const unsigned short* w0 = Wpk + (((ob0 * 16 + kk) * 64 + lane) * 8);
        const unsigned short* w1 = Wpk + (((ob1 * 16 + kk) * 64 + lane) * 8);
        const unsigned short* w2 = Wpk + ((((ob0 + 8) * 16 + kk) * 64 + lane) * 8);
        const unsigned short* w3 = Wpk + ((((ob1 + 8) * 16 + kk) * 64 + lane) * 8);
        short8v h0 = *(const short8v*)w0;
        short8v h1 = *(const short8v*)w1;
        short8v h2 = *(const short8v*)w2;
        short8v h3 = *(const short8v*)w3;
        acc0 = MFMA32(a, h0, acc0);
        acc1 = MFMA32(a, h1, acc1);
        acc2 = MFMA32(a, h2, acc2);
        acc3 = MFMA32(a, h3, acc3);
    }
    __syncthreads();
    #pragma unroll
    for (int p = 0; p < 2; ++p) {
        const f32x16& z1v = p ? acc1 : acc0;
        const f32x16& z2v = p ? acc3 : acc2;
        int o = (p ? ob1 : ob0) * 32 + (lane & 31);
        float b1 = bias[o], b2 = bias[o + 256];
        #pragma unroll
        for (int rr = 0; rr < 16; ++rr) {
            int lloc = (rr & 3) + 8 * (rr >> 2) + 4 * (lane >> 5);
            Smt[lloc * 264 + o] = f2bf(fast_sigmoid_mul(z1v[rr] + b1, z2v[rr] + b2));
        }
    }
    __syncthreads();
    {
        const unsigned short* xr = xbf + ((size_t)b * H_DIM + tid_t) * L_SEQ + lt0;
        #pragma unroll
        for (int u8 = 0; u8 < 4; ++u8) {
            union { uint4 v; unsigned short s[8]; } q;
            q.v = *(const uint4*)(xr + u8 * 8);
            #pragma unroll
            for (int j = 0; j < 8; ++j) {
                int idx = (u8 * 8 + j) * 264 + tid_t;
                Smt[idx] = f2bf(bf2f(Smt[idx]) + bf2f(q.s[j]));
            }
        }
    }
    __syncthreads();
    #pragma unroll
    for (int rr = 0; rr < 8; ++rr) {
        int row = rr * 4 + wv4;
        ushort4 hv = *(const ushort4*)(Smt + row * 264 + lane * 4);
        float v0 = bf2f(hv.x), v1 = bf2f(hv.y), v2 = bf2f(hv.z), v3 = bf2f(hv.w);
        float s = v0 + v1 + v2 + v3;
        float sq = v0 * v0 + v1 * v1 + v2 * v2 + v3 * v3;
        #pragma unroll
        for (int st = 1; st < 64; st <<= 1) {
            s += __shfl_xor(s, st);
            sq += __shfl_xor(sq, st);
        }
        float mean = s * (1.f / H_DIM);
        float var = sq * (1.f / H_DIM) - mean * mean;
        float rstd = rsqrtf(var + 1e-5f);
        ushort4 ov;
        ov.x = f2bf((v0 - mean) * rstd * g4.x + b4.x);
        ov.y = f2bf((v1 - mean) * rstd * g4.y + b4.y);
        ov.z = f2bf((v2 - mean) * rstd * g4.z + b4.z);
        ov.w = f2bf((v3 - mean) * rstd * g4.w + b4.w);
        *(ushort4*)(Smt + row * 264 + lane * 4) = ov;
    }
    __syncthreads();
    {
        unsigned short* dst = xbf + ((size_t)b * H_DIM + tid_t) * L_SEQ + lt0;
        #pragma unroll
        for (int u8 = 0; u8 < 4; ++u8) {
            union { uint4 v; unsigned short s[8]; } pk;
            #pragma unroll
            for (int j = 0; j < 8; ++j) {
                pk.s[j] = Smt[(u8 * 8 + j) * 264 + tid_t];
                if constexpr (LAST) msum += bf2f(pk.s[j]);
            }
            *(uint4*)(dst + u8 * 8) = pk.v;
        }
    }
    if constexpr (LAST)
        atomicAdd(&meanb[b * H_DIM + tid_t], msum);
}

// ---------------------------------------------------------------------------
__global__ __launch_bounds__(256) void decode(
    const float* __restrict__ meanb, const float* __restrict__ dw,
    const float* __restrict__ db, float* __restrict__ out)
{
    int i = threadIdx.x;
    if (i >= BATCH * 10) return;
    int b = i / 10, d = i % 10;
    float s = db[d];
    for (int h = 0; h < H_DIM; ++h)
        s = fmaf(meanb[b * H_DIM + h] * (1.f / L_SEQ), dw[d * H_DIM + h], s);
    out[i] = s;
}

// ---------------------------------------------------------------------------
extern "C" void kernel_launch(void* const* d_in, const int* in_sizes, int n_in,
                              void* d_out, int out_size, void* d_ws, size_t ws_size,
                              hipStream_t stream)
{
    const float* x_in = (const float*)d_in[0];
    const float* cw[3] = {(const float*)d_in[1], (const float*)d_in[7],  (const float*)d_in[13]};
    const float* cb[3] = {(const float*)d_in[2], (const float*)d_in[8],  (const float*)d_in[14]};
    const float* bg[3] = {(const float*)d_in[3], (const float*)d_in[9],  (const float*)d_in[15]};
    const float* bb[3] = {(const float*)d_in[4], (const float*)d_in[10], (const float*)d_in[16]};
    const float* bm[3] = {(const float*)d_in[5], (const float*)d_in[11], (const float*)d_in[17]};
    const float* bv[3] = {(const float*)d_in[6], (const float*)d_in[12], (const float*)d_in[18]};
    const float* log_dt   = (const float*)d_in[19];
    const float* A_re_log = (const float*)d_in[20];
    const float* A_im     = (const float*)d_in[21];
    const float* C_re     = (const float*)d_in[22];
    const float* C_im     = (const float*)d_in[23];
    const float* Dv       = (const float*)d_in[24];
    const float* out_w    = (const float*)d_in[25];
    const float* out_b    = (const float*)d_in[26];
    const float* ln_g     = (const float*)d_in[27];
    const float* ln_b     = (const float*)d_in[28];
    const float* dec_w    = (const float*)d_in[29];
    const float* dec_b    = (const float*)d_in[30];

    const size_t PLANE = (size_t)BATCH * H_DIM * L_SEQ;       // 16,777,216 floats
    float* ws = (float*)d_ws;
    unsigned short* xbf = (unsigned short*)ws;                // [B][256][L] bf16
    float* X   = ws + PLANE;            // conv temps -> per-layer matrices
    unsigned short* ybf = (unsigned short*)(ws + 2 * PLANE);  // [B][H][L] bf16
    float* tail = ws + 2 * PLANE + PLANE / 2;
    unsigned short* Wpk = (unsigned short*)tail;              // 1,048,576 us
    float* Ktab  = tail + 524288;                             // (unused, reserved)
    float* wqbuf = Ktab + 32768;
    float* meanb = wqbuf + 32768;
    unsigned short* Wc2 = (unsigned short*)(meanb + 4096);
    float* Bs2 = (float*)(Wc2 + 81920);
    unsigned short* Wc3 = (unsigned short*)(Bs2 + 128);
    float* Bs3 = (float*)(Wc3 + 196608);

    unsigned short* X_us = (unsigned short*)X;
    unsigned short* Vpk = X_us;
    unsigned short* Epk = X_us + 8388608;
    unsigned short* Tpk = X_us + 16777216;

    precompute_wpk<<<256, 256, 0, stream>>>(out_w, Wpk);
    pack_conv<64, 5, 128><<<20, 256, 0, stream>>>(cw[1], bg[1], bv[1], cb[1], bm[1], bb[1], Wc2, Bs2);
    pack_conv<128, 3, 256><<<48, 256, 0, stream>>>(cw[2], bg[2], bv[2], cb[2], bm[2], bb[2], Wc3, Bs3);
    hipMemsetAsync(meanb, 0, BATCH * H_DIM * sizeof(float), stream);

    // Encoder: x_in -> c1p (padded) -> c2p (padded) -> xbf (bf16)
    float* c1p = X;
    float* c2p = X + (size_t)BATCH * 64 * LPAD;
    conv_bn_relu_f<1, 7><<<dim3(16, 2, 16), 256, 0, stream>>>(
        x_in, c1p, cw[0], cb[0], bg[0], bb[0], bm[0], bv[0], 64);
    conv_mfma<64, 5, 128, true, false><<<dim3(128, 16), 256, 0, stream>>>(c1p, c2p, Wc2, Bs2);
    conv_mfma<128, 3, 256, false, true><<<dim3(128, 16), 256, 0, stream>>>(c2p, xbf, Wc3, Bs3);

    for (int l = 0; l < 4; ++l) {
        mats_gen<<<256, 256, 0, stream>>>(log_dt, A_re_log, A_im, C_re, C_im, Dv, l,
                                          Vpk, Epk, Tpk, wqbuf);
        s4d_fused<<<dim3(256, 4), dim3(256), 0, stream>>>(xbf, Vpk, Epk, Tpk, wqbuf, ybf);
        if (l < 3)
            linear_glu_ln<false><<<dim3(64, 16), dim3(512), 0, stream>>>(
                ybf, Wpk + (size_t)l * 262144, out_b + l * 512,
                ln_g + l * H_DIM, ln_b + l * H_DIM, xbf, meanb);
        else
            linear_glu_ln<true><<<dim3(64, 16), dim3(512), 0, stream>>>(
                ybf, Wpk + (size_t)l * 262144, out_b + l * 512,
                ln_g + l * H_DIM, ln_b + l * H_DIM, xbf, meanb);
    }

    decode<<<dim3(1), 256, 0, stream>>>(meanb, dec_w, dec_b, (float*)d_out);
}

// Round 26
// 547.279 us; speedup vs baseline: 1.0602x; 1.0602x over previous
//
#include <hip/hip_runtime.h>
#include <cstdint>
#include <cstddef>

#define L_SEQ 4096
#define H_DIM 256
#define N_MODES 64
#define BATCH 16
#define QCH 128
#define NCHUNK 32
#define LPAD (L_SEQ + 8)

typedef __attribute__((ext_vector_type(8))) short short8v;
typedef __attribute__((ext_vector_type(16))) float f32x16;

#define MFMA32(a, b, c) __builtin_amdgcn_mfma_f32_32x32x16_bf16((a), (b), (c), 0, 0, 0)

__device__ __forceinline__ unsigned short f2bf(float f) {
    unsigned u = __float_as_uint(f);
    u = u + 0x7fff + ((u >> 16) & 1);
    return (unsigned short)(u >> 16);
}
__device__ __forceinline__ float bf2f(unsigned short h) {
    return __uint_as_float(((unsigned)h) << 16);
}
// wave-local LDS ordering fence (rule #18): orders this wave's DS ops without
// a block-wide barrier. Used where the LDS tile is wave-private.
__device__ __forceinline__ void wave_lds_fence() {
    asm volatile("s_waitcnt lgkmcnt(0)" ::: "memory");
    __builtin_amdgcn_sched_barrier(0);
}
// tanh-GELU via sigmoid identity: 0.5*y*(1+tanh(z)) = y*sigmoid(2z), fast exp
__device__ __forceinline__ float fast_gelu(float y) {
    float t = fmaf(0.044715f * y * y, y, y);
    return y / (1.f + __expf(-1.5957691f * t));
}
__device__ __forceinline__ float fast_sigmoid_mul(float z1, float z2) {
    return z1 / (1.f + __expf(-z2));
}

// packed B-fragment position for 32x32x16 bf16: entry (k, col)
__device__ __forceinline__ int bpos(int k, int col) {
    return ((col >> 5) * 8 + (k >> 4)) * 512 + ((col & 31) + 32 * ((k >> 3) & 1)) * 8 + (k & 7);
}
__device__ __forceinline__ void whi(unsigned short* M, int k, int col, float v) {
    M[bpos(k, col)] = f2bf(v);
}

// ---------------------------------------------------------------------------
// Per-layer S4D matrices (hi-plane only) + fused Toeplitz fill, DIRECT FORM:
// w^d = exp(dr*d)*(cos(di*d), sin(di*d)) -- every (d,n) entry independent.
// Grid 256 (one block per h); d-loop strided over the 4 waves.
// ---------------------------------------------------------------------------
__global__ __launch_bounds__(256) void mats_gen(
    const float* __restrict__ log_dt, const float* __restrict__ A_re_log,
    const float* __restrict__ A_im, const float* __restrict__ C_re,
    const float* __restrict__ C_im, const float* __restrict__ Dv, int layer,
    unsigned short* __restrict__ Vpk, unsigned short* __restrict__ Epk,
    unsigned short* __restrict__ Tpk, float* __restrict__ wqbuf)
{
    __shared__ float Kl[128];
    const int wv = threadIdx.x >> 6, n = threadIdx.x & 63;
    const int h = blockIdx.x;
    const int idx = (layer * H_DIM + h) * N_MODES + n;
    float dt = expf(log_dt[layer * H_DIM + h]);
    float Ar = -expf(A_re_log[idx]);
    float Ai = A_im[idx];
    float dr = Ar * dt, di = Ai * dt;
    float Cr = C_re[idx], Ci = C_im[idx];
    // w = exp(dr)*(cos di, sin di); c2 = 2*C*(w-1)/A
    float er1 = expf(dr);
    float wr = er1 * cosf(di), wi = er1 * sinf(di);
    float nr = wr - 1.f, ni = wi;
    float pr_ = Cr * nr - Ci * ni;
    float pi_ = Cr * ni + Ci * nr;
    float inv = 1.f / (Ar * Ar + Ai * Ai);
    float c2r = 2.f * (pr_ * Ar + pi_ * Ai) * inv;
    float c2i = 2.f * (pi_ * Ar - pr_ * Ai) * inv;
    float Dh = Dv[layer * H_DIM + h];
    unsigned short* Vh = Vpk + h * 32768;
    unsigned short* Eh = Epk + h * 32768;

    for (int d = wv; d <= QCH; d += 4) {
        float fd = (float)d;
        float erd = expf(dr * fd);
        float pr = erd * cosf(di * fd);     // Re(w^d)
        float pi = erd * sinf(di * fd);     // Im(w^d)
        float qr = c2r * pr - c2i * pi;     // c2 * w^d
        float qi = c2r * pi + c2i * pr;
        if (d <= QCH - 1) {
            int t = QCH - 1 - d;
            whi(Vh, t, 2 * n, pr);
            whi(Vh, t, 2 * n + 1, pi);
            float s = qr;                   // K[d] = sum_n Re(c2 w^d) (+D at 0)
            #pragma unroll
            for (int st = 1; st < 64; st <<= 1) s += __shfl_xor(s, st);
            if (n == 0) Kl[d] = s + (d == 0 ? Dh : 0.f);
        }
        if (d >= 1) {
            int t = d - 1;
            whi(Eh, 2 * n, t, qr);
            whi(Eh, 2 * n + 1, t, -qi);
        }
        if (d == QCH) {
            wqbuf[(h * 64 + n) * 2 + 0] = pr;   // wQ = w^128
            wqbuf[(h * 64 + n) * 2 + 1] = pi;
        }
    }
    __syncthreads();
    // Toeplitz fill (hi only): B[j][t] = K[t-j]; 32 groups split over 4 waves
    unsigned short* Th = Tpk + h * 32768;
    for (int g = wv; g < 32; g += 4) {
        int nt = g >> 3, ks = g & 7;
        int col = nt * 32 + (n & 31);
        int k0 = ks * 16 + (n >> 5) * 8;
        union { unsigned short s[8]; uint4 v; } hi;
        #pragma unroll
        for (int j = 0; j < 8; ++j) {
            int d = col - (k0 + j);
            hi.s[j] = f2bf((d >= 0) ? Kl[d] : 0.f);
        }
        *(uint4*)(Th + (nt * 8 + ks) * 512 + n * 8) = hi.v;
    }
}

// ---------------------------------------------------------------------------
// Conv weight pack (BN-folded) into MFMA B-frag order per shift k, + bias.
// ---------------------------------------------------------------------------
template<int CI, int K, int CO>
__global__ __launch_bounds__(256) void pack_conv(
    const float* __restrict__ wg, const float* __restrict__ g,
    const float* __restrict__ v, const float* __restrict__ cb,
    const float* __restrict__ m, const float* __restrict__ bb,
    unsigned short* __restrict__ Wc, float* __restrict__ Bs)
{
    constexpr int NT = CO / 32, KS = CI / 16;
    int t = blockIdx.x * 256 + threadIdx.x;
    if (t < CO) Bs[t] = (cb[t] - m[t]) * g[t] * rsqrtf(v[t] + 1e-5f) + bb[t];
    if (t >= K * NT * KS * 64) return;
    int lane = t & 63;
    int rest = t >> 6;
    int ks = rest % KS;
    int nt = (rest / KS) % NT;
    int k = rest / (KS * NT);
    int co = nt * 32 + (lane & 31);
    int ci0 = ks * 16 + (lane >> 5) * 8;
    float s = g[co] * rsqrtf(v[co] + 1e-5f);
    union { unsigned short s_[8]; uint4 v_; } hi;
    #pragma unroll
    for (int j = 0; j < 8; ++j) {
        float f = wg[((size_t)co * CI + ci0 + j) * K + k] * s;
        hi.s_[j] = f2bf(f);
    }
    size_t base = ((size_t)(k * NT + nt) * KS + ks) * 512 + lane * 8;
    *(uint4*)(Wc + base) = hi.v_;
}

// ---------------------------------------------------------------------------
// Conv1 (CI=1): validated VALU version.
// ---------------------------------------------------------------------------
template<int CI, int K>
__global__ __launch_bounds__(256) void conv_bn_relu_f(
    const float* __restrict__ in, float* __restrict__ out,
    const float* __restrict__ wg, const float* __restrict__ cb,
    const float* __restrict__ g, const float* __restrict__ bb,
    const float* __restrict__ m, const float* __restrict__ v, int CO)
{
    const int wv = threadIdx.x >> 6, lane = threadIdx.x & 63;
    const int b = blockIdx.z;
    const int co0 = __builtin_amdgcn_readfirstlane(blockIdx.y * 32 + wv * 8);
    const int l = blockIdx.x * 256 + lane * 4;
    const int OFF = K / 2;
    float acc[8][4] = {};
    const float* inb = in + (size_t)b * CI * L_SEQ;
    for (int ci = 0; ci < CI; ++ci) {
        const float* row = inb + (size_t)ci * L_SEQ;
        float win[12];
        #pragma unroll
        for (int d = 0; d < 12; ++d) {
            int li = l - 4 + d;
            win[d] = (li >= 0 && li < L_SEQ) ? row[li] : 0.f;
        }
        #pragma unroll
        for (int cc = 0; cc < 8; ++cc) {
            #pragma unroll
            for (int k = 0; k < K; ++k) {
                float wk = wg[((size_t)(co0 + cc) * CI + ci) * K + k];
                #pragma unroll
                for (int j = 0; j < 4; ++j)
                    acc[cc][j] = fmaf(win[4 + j + k - OFF], wk, acc[cc][j]);
            }
        }
    }
    #pragma unroll
    for (int cc = 0; cc < 8; ++cc) {
        int co = co0 + cc;
        float s = g[co] * rsqrtf(v[co] + 1e-5f);
        float sh = (cb[co] - m[co]) * s + bb[co];
        float* orow = out + ((size_t)b * CO + co) * LPAD + 4;
        float4 o4;
        o4.x = fmaxf(fmaf(acc[cc][0], s, sh), 0.f);
        o4.y = fmaxf(fmaf(acc[cc][1], s, sh), 0.f);
        o4.z = fmaxf(fmaf(acc[cc][2], s, sh), 0.f);
        o4.w = fmaxf(fmaf(acc[cc][3], s, sh), 0.f);
        *(float4*)(orow + l) = o4;
        if (blockIdx.x == 0 && lane == 0)
            *(float4*)(orow - 4) = make_float4(0.f, 0.f, 0.f, 0.f);
        if (blockIdx.x == gridDim.x - 1 && lane == 63)
            *(float4*)(orow + L_SEQ) = make_float4(0.f, 0.f, 0.f, 0.f);
    }
}

// ---------------------------------------------------------------------------
// Conv via MFMA implicit GEMM, hi-plane only (r13 numerics: A is bf16-rounded,
// lo corrections below noise floor). OBF: store output as bf16 [B][CO][L].
// ---------------------------------------------------------------------------
template<int CI, int K, int CO, bool POUT, bool OBF>
__global__ __launch_bounds__(256) void conv_mfma(
    const float* __restrict__ in, void* __restrict__ outv,
    const unsigned short* __restrict__ Wc, const float* __restrict__ Bs)
{
    constexpr int NT = CO / 32, KS = CI / 16, OBS = NT / 4, OFF = K / 2;
    __shared__ __align__(16) unsigned short A0[40 * CI];
    __shared__ __align__(16) char vtraw[32 * (CO + 8) * (OBF ? 2 : 4)];
    const int b = blockIdx.y, l0 = blockIdx.x * 32;
    const int wv = threadIdx.x >> 6, lane = threadIdx.x & 63;
    const float* inb = in + (size_t)b * CI * LPAD + l0;
    for (int e = threadIdx.x; e < CI * 10; e += 256) {
        int ci = e / 10, f4 = e - ci * 10;
        float4 q = *(const float4*)(inb + (size_t)ci * LPAD + f4 * 4);
        #pragma unroll
        for (int j = 0; j < 4; ++j) {
            int row = f4 * 4 + j;
            int bo = ((row * CI + ci) * 2) ^ ((row & 7) << 4);
            *(unsigned short*)((char*)A0 + bo) = f2bf((&q.x)[j]);
        }
    }
    __syncthreads();
    f32x16 acc0 = {}, acc1 = {};
    #pragma unroll
    for (int k = 0; k < K; ++k) {
        #pragma unroll
        for (int ks = 0; ks < KS; ++ks) {
            int row = (lane & 31) + 4 + k - OFF;
            int abyte = ((row * CI + ks * 16 + (lane >> 5) * 8) * 2) ^ ((row & 7) << 4);
            short8v ah = *(const short8v*)((const char*)A0 + abyte);
            {
                const unsigned short* wb = Wc + ((size_t)(k * NT + wv * OBS) * KS + ks) * 512 + lane * 8;
                short8v bh = *(const short8v*)wb;
                acc0 = MFMA32(ah, bh, acc0);
            }
            if constexpr (OBS == 2) {
                const unsigned short* wb = Wc + ((size_t)(k * NT + wv * OBS + 1) * KS + ks) * 512 + lane * 8;
                short8v bh = *(const short8v*)wb;
                acc1 = MFMA32(ah, bh, acc1);
            }
        }
    }
    __syncthreads();   // A-tile reads done before vtraw repurpose ordering
    if constexpr (OBF) {
        unsigned short* vtb = (unsigned short*)vtraw;   // [32][CO+8] bf16
        int co = (wv * OBS) * 32 + (lane & 31);
        float bs = Bs[co];
        #pragma unroll
        for (int r = 0; r < 16; ++r) {
            int lr = (r & 3) + 8 * (r >> 2) + 4 * (lane >> 5);
            vtb[lr * (CO + 8) + co] = f2bf(fmaxf(acc0[r] + bs, 0.f));
        }
        if constexpr (OBS == 2) {
            int co1 = co + 32;
            float bs1 = Bs[co1];
            #pragma unroll
            for (int r = 0; r < 16; ++r) {
                int lr = (r & 3) + 8 * (r >> 2) + 4 * (lane >> 5);
                vtb[lr * (CO + 8) + co1] = f2bf(fmaxf(acc1[r] + bs1, 0.f));
            }
        }
        __syncthreads();
        unsigned short* orow = (unsigned short*)outv
            + ((size_t)b * CO + threadIdx.x) * L_SEQ + l0;
        #pragma unroll
        for (int u8 = 0; u8 < 4; ++u8) {
            union { unsigned short s[8]; uint4 v; } pk;
            #pragma unroll
            for (int j = 0; j < 8; ++j)
                pk.s[j] = vtb[(u8 * 8 + j) * (CO + 8) + threadIdx.x];
            *(uint4*)(orow + u8 * 8) = pk.v;
        }
    } else {
        float* vt = (float*)vtraw;                      // [32][CO+8] fp32
        {
            int co = (wv * OBS) * 32 + (lane & 31);
            float bs = Bs[co];
            #pragma unroll
            for (int r = 0; r < 16; ++r) {
                int lr = (r & 3) + 8 * (r >> 2) + 4 * (lane >> 5);
                vt[lr * (CO + 8) + co] = fmaxf(acc0[r] + bs, 0.f);
            }
            if constexpr (OBS == 2) {
                int co1 = co + 32;
                float bs1 = Bs[co1];
                #pragma unroll
                for (int r = 0; r < 16; ++r) {
                    int lr = (r & 3) + 8 * (r >> 2) + 4 * (lane >> 5);
                    vt[lr * (CO + 8) + co1] = fmaxf(acc1[r] + bs1, 0.f);
                }
            }
        }
        __syncthreads();
        float* out = (float*)outv;
        int co = threadIdx.x & 127, lh = threadIdx.x >> 7;
        float* rowb = out + ((size_t)b * CO + co) * LPAD;
        float* orow = rowb + 4 + l0 + lh * 16;
        #pragma unroll
        for (int u4 = 0; u4 < 4; ++u4) {
            float4 o;
            o.x = vt[(lh * 16 + u4 * 4 + 0) * (CO + 8) + co];
            o.y = vt[(lh * 16 + u4 * 4 + 1) * (CO + 8) + co];
            o.z = vt[(lh * 16 + u4 * 4 + 2) * (CO + 8) + co];
            o.w = vt[(lh * 16 + u4 * 4 + 3) * (CO + 8) + co];
            *(float4*)(orow + u4 * 4) = o;
        }
        if (blockIdx.x == 0 && lh == 0)
            *(float4*)(rowb) = make_float4(0.f, 0.f, 0.f, 0.f);
        if (blockIdx.x == gridDim.x - 1 && lh == 1)
            *(float4*)(rowb + 4 + L_SEQ) = make_float4(0.f, 0.f, 0.f, 0.f);
    }
}

// ---------------------------------------------------------------------------
// Fused S4D core v9 (r24 validated best): bf16 x-stream; C+D merged;
// fast GELU; wave-local fences; 4 live accumulators (ILP > occupancy here —
// r25's register-diet split regressed).
// ---------------------------------------------------------------------------
__global__ __launch_bounds__(256) void s4d_fused(
    const unsigned short* __restrict__ u,    // [B][256][L] bf16
    const unsigned short* __restrict__ Vpk,
    const unsigned short* __restrict__ Epk,
    const unsigned short* __restrict__ Tpk,
    const float* __restrict__ wqbuf,
    unsigned short* __restrict__ ybf)        // [B][H][L] bf16
{
    __shared__ __align__(16) unsigned short Sb[4][4096];
    const int h = blockIdx.x;
    const int wv = threadIdx.x >> 6, lane = threadIdx.x & 63;
    const int b = blockIdx.y * 4 + wv;
    const unsigned short* urow = u + ((size_t)b * H_DIM + h) * L_SEQ;
    const int c = lane & 31;
    const int khalf = (lane >> 5) * 8;
    char* Sw = (char*)Sb[wv];

    short8v uh[8];
    #pragma unroll
    for (int ks = 0; ks < 8; ++ks)
        uh[ks] = *(const short8v*)(urow + c * 128 + ks * 16 + khalf);

    f32x16 acc0 = {}, acc1 = {}, acc2 = {}, acc3 = {};
    {
        const unsigned short* Vh = Vpk + h * 32768;
        #pragma unroll
        for (int ks = 0; ks < 8; ++ks) {
            const unsigned short* vb = Vh + ks * 512 + lane * 8;
            short8v b0h = *(const short8v*)(vb);
            short8v b1h = *(const short8v*)(vb + 4096);
            short8v b2h = *(const short8v*)(vb + 8192);
            short8v b3h = *(const short8v*)(vb + 12288);
            acc0 = MFMA32(uh[ks], b0h, acc0);
            acc1 = MFMA32(uh[ks], b1h, acc1);
            acc2 = MFMA32(uh[ks], b2h, acc2);
            acc3 = MFMA32(uh[ks], b3h, acc3);
        }
    }
    #pragma unroll
    for (int nt = 0; nt < 4; ++nt) {
        const f32x16& a = nt == 0 ? acc0 : nt == 1 ? acc1 : nt == 2 ? acc2 : acc3;
        int col = nt * 32 + (lane & 31);
        #pragma unroll
        for (int r = 0; r < 16; ++r) {
            int cc = (r & 3) + 8 * (r >> 2) + 4 * (lane >> 5);
            int boff = (cc * 256 + col * 2) ^ ((cc & 15) << 4);
            *(unsigned short*)(Sw + boff) = f2bf(a[r]);
        }
    }
    wave_lds_fence();   // scatter ordered before prefix reads (wave-private tile)
    {
        const float2 wq = *(const float2*)(wqbuf + ((size_t)h * 64 + lane) * 2);
        float sr[NCHUNK], si[NCHUNK];
        #pragma unroll
        for (int cc = 0; cc < NCHUNK; ++cc) {
            int boff = (cc * 256 + lane * 4) ^ ((cc & 15) << 4);
            sr[cc] = bf2f(*(const unsigned short*)(Sw + boff));
            si[cc] = bf2f(*(const unsigned short*)(Sw + boff + 2));
        }
        float Pr = 0.f, Pi = 0.f;
        #pragma unroll
        for (int cc = 0; cc < NCHUNK; ++cc) {
            int boff = (cc * 256 + lane * 4) ^ ((cc & 15) << 4);
            *(unsigned short*)(Sw + boff) = f2bf(Pr);
            *(unsigned short*)(Sw + boff + 2) = f2bf(Pi);
            float npr = fmaf(wq.x, Pr, fmaf(-wq.y, Pi, sr[cc]));
            float npi = fmaf(wq.x, Pi, fmaf(wq.y, Pr, si[cc]));
            Pr = npr; Pi = npi;
        }
    }
    wave_lds_fence();   // P writes ordered before phase-C vector reads
    acc0 = (f32x16){}; acc1 = (f32x16){}; acc2 = (f32x16){}; acc3 = (f32x16){};
    {
        const unsigned short* Eh = Epk + h * 32768;
        const unsigned short* Th = Tpk + h * 32768;
        const int swzc = (c & 15) << 4;
        #pragma unroll
        for (int ks = 0; ks < 8; ++ks) {
            int boff = (c * 256 + (ks * 16 + khalf) * 2) ^ swzc;
            short8v ah = *(const short8v*)(Sw + boff);
            const unsigned short* eb = Eh + ks * 512 + lane * 8;
            const unsigned short* tb = Th + ks * 512 + lane * 8;
            short8v e0 = *(const short8v*)(eb);
            short8v e1 = *(const short8v*)(eb + 4096);
            short8v e2 = *(const short8v*)(eb + 8192);
            short8v e3 = *(const short8v*)(eb + 12288);
            short8v t0 = *(const short8v*)(tb);
            short8v t1 = *(const short8v*)(tb + 4096);
            short8v t2 = *(const short8v*)(tb + 8192);
            short8v t3 = *(const short8v*)(tb + 12288);
            acc0 = MFMA32(ah, e0, acc0);
            acc1 = MFMA32(ah, e1, acc1);
            acc2 = MFMA32(ah, e2, acc2);
            acc3 = MFMA32(ah, e3, acc3);
            acc0 = MFMA32(uh[ks], t0, acc0);
            acc1 = MFMA32(uh[ks], t1, acc1);
            acc2 = MFMA32(uh[ks], t2, acc2);
            acc3 = MFMA32(uh[ks], t3, acc3);
        }
    }
    unsigned short* yrow = ybf + ((size_t)b * H_DIM + h) * L_SEQ;
    #pragma unroll
    for (int nt = 0; nt < 4; ++nt) {
        const f32x16& a = nt == 0 ? acc0 : nt == 1 ? acc1 : nt == 2 ? acc2 : acc3;
        int t = nt * 32 + (lane & 31);
        #pragma unroll
        for (int r = 0; r < 16; ++r) {
            int cc = (r & 3) + 8 * (r >> 2) + 4 * (lane >> 5);
            yrow[cc * QCH + t] = f2bf(fast_gelu(a[r]));
        }
    }
}

// ---------------------------------------------------------------------------
// W -> packed MFMA B-fragment order (GLU linear).
// ---------------------------------------------------------------------------
__global__ __launch_bounds__(256) void precompute_wpk(
    const float* __restrict__ W, unsigned short* __restrict__ Wpk)
{
    int t = blockIdx.x * 256 + threadIdx.x;
    if (t >= 4 * 16 * 16 * 64) return;
    int lane = t & 63;
    int kk = (t >> 6) & 15;
    int ob = (t >> 10) & 15;
    int layer = t >> 14;
    int o = ob * 32 + (lane & 31);
    int k0 = kk * 16 + (lane >> 5) * 8;
    const float* src = W + ((size_t)layer * 512 + o) * H_DIM + k0;
    union { unsigned short s[8]; uint4 v; } hi;
    #pragma unroll
    for (int j = 0; j < 8; ++j) hi.s[j] = f2bf(src[j]);
    size_t base = (size_t)layer * 262144 + ((size_t)((ob * 16 + kk) * 64 + lane) * 8);
    *(uint4*)(Wpk + base) = hi.v;
}

// ---------------------------------------------------------------------------
// Output linear (H->2H) MFMA + GLU + residual + LayerNorm, fused.
// v4 (validated r19/r21/r24 best): 512-thread blocks, wave-group per tile.
// LAST: accumulate per-(b,h) sums into meanb via atomicAdd (pool fusion).
// ---------------------------------------------------------------------------
template<bool LAST>
__global__ __launch_bounds__(512) void linear_glu_ln(
    const unsigned short* __restrict__ ybf,
    const unsigned short* __restrict__ Wpk,
    const float* __restrict__ bias,
    const float* __restrict__ lg, const float* __restrict__ lb,
    unsigned short* __restrict__ xbf, float* __restrict__ meanb)
{
    __shared__ __align__(16) unsigned short Sm[2][8448];
    const int lane = threadIdx.x & 63;
    const int t = threadIdx.x >> 8;          // tile group (0 or 1)
    const int tid_t = threadIdx.x & 255;     // thread id within tile group
    const int wv4 = (threadIdx.x >> 6) & 3;  // wave within tile group
    const int b = blockIdx.y;
    const int l0 = blockIdx.x * 64;
    const int lt0 = l0 + t * 32;
    unsigned short* Smt = Sm[t];

    {
        const unsigned short* ybase = ybf + (size_t)b * H_DIM * L_SEQ + lt0;
        #pragma unroll
        for (int p = 0; p < 4; ++p) {
            int e = tid_t + p * 256;
            int hh = e >> 2, c4 = e & 3;
            union { uint4 v; unsigned short s[8]; } qv;
            qv.v = *(const uint4*)(ybase + (size_t)hh * L_SEQ + c4 * 8);
            #pragma unroll
            for (int j = 0; j < 8; ++j) {
                int lloc = c4 * 8 + j;
                int byteoff = (lloc << 9) + hh * 2;
                byteoff ^= ((lloc & 15) << 4);
                *(unsigned short*)((char*)Smt + byteoff) = qv.s[j];
            }
        }
    }
    __syncthreads();

    const int ob0 = 2 * wv4, ob1 = 2 * wv4 + 1;
    const int r = lane & 31;
    const float4 g4 = *(const float4*)(lg + lane * 4);
    const float4 b4 = *(const float4*)(lb + lane * 4);
    float msum = 0.f;

    f32x16 acc0 = {}, acc1 = {}, acc2 = {}, acc3 = {};
    #pragma unroll 4
    for (int kk = 0; kk < 16; ++kk) {
        int abyte = (r << 9) | (kk * 32 + (lane >> 5) * 16);
        abyte ^= ((r & 15) << 4);
        short8v a = *(const short8v*)((char*)Smt + abyte);
        const unsigned short* w0 = Wpk + (((ob0 * 16 + kk) * 64 + lane) * 8);
        const unsigned short* w1 = Wpk + (((ob1 * 16 + kk) * 64 + lane) * 8);
        const unsigned short* w2 = Wpk + ((((ob0 + 8) * 16 + kk) * 64 + lane) * 8);
        const unsigned short* w3 = Wpk + ((((ob1 + 8) * 16 + kk) * 64 + lane) * 8);
        short8v h0 = *(const short8v*)w0;
        short8v h1 = *(const short8v*)w1;
        short8v h2 = *(const short8v*)w2;
        short8v h3 = *(const short8v*)w3;
        acc0 = MFMA32(a, h0, acc0);
        acc1 = MFMA32(a, h1, acc1);
        acc2 = MFMA32(a, h2, acc2);
        acc3 = MFMA32(a, h3, acc3);
    }
    __syncthreads();
    #pragma unroll
    for (int p = 0; p < 2; ++p) {
        const f32x16& z1v = p ? acc1 : acc0;
        const f32x16& z2v = p ? acc3 : acc2;
        int o = (p ? ob1 : ob0) * 32 + (lane & 31);
        float b1 = bias[o], b2 = bias[o + 256];
        #pragma unroll
        for (int rr = 0; rr < 16; ++rr) {
            int lloc = (rr & 3) + 8 * (rr >> 2) + 4 * (lane >> 5);
            Smt[lloc * 264 + o] = f2bf(fast_sigmoid_mul(z1v[rr] + b1, z2v[rr] + b2));
        }
    }
    __syncthreads();
    {
        const unsigned short* xr = xbf + ((size_t)b * H_DIM + tid_t) * L_SEQ + lt0;
        #pragma unroll
        for (int u8 = 0; u8 < 4; ++u8) {
            union { uint4 v; unsigned short s[8]; } q;
            q.v = *(const uint4*)(xr + u8 * 8);
            #pragma unroll
            for (int j = 0; j < 8; ++j) {
                int idx = (u8 * 8 + j) * 264 + tid_t;
                Smt[idx] = f2bf(bf2f(Smt[idx]) + bf2f(q.s[j]));
            }
        }
    }
    __syncthreads();
    #pragma unroll
    for (int rr = 0; rr < 8; ++rr) {
        int row = rr * 4 + wv4;
        ushort4 hv = *(const ushort4*)(Smt + row * 264 + lane * 4);
        float v0 = bf2f(hv.x), v1 = bf2f(hv.y), v2 = bf2f(hv.z), v3 = bf2f(hv.w);
        float s = v0 + v1 + v2 + v3;
        float sq = v0 * v0 + v1 * v1 + v2 * v2 + v3 * v3;
        #pragma unroll
        for (int st = 1; st < 64; st <<= 1) {
            s += __shfl_xor(s, st);
            sq += __shfl_xor(sq, st);
        }
        float mean = s * (1.f / H_DIM);
        float var = sq * (1.f / H_DIM) - mean * mean;
        float rstd = rsqrtf(var + 1e-5f);
        ushort4 ov;
        ov.x = f2bf((v0 - mean) * rstd * g4.x + b4.x);
        ov.y = f2bf((v1 - mean) * rstd * g4.y + b4.y);
        ov.z = f2bf((v2 - mean) * rstd * g4.z + b4.z);
        ov.w = f2bf((v3 - mean) * rstd * g4.w + b4.w);
        *(ushort4*)(Smt + row * 264 + lane * 4) = ov;
    }
    __syncthreads();
    {
        unsigned short* dst = xbf + ((size_t)b * H_DIM + tid_t) * L_SEQ + lt0;
        #pragma unroll
        for (int u8 = 0; u8 < 4; ++u8) {
            union { uint4 v; unsigned short s[8]; } pk;
            #pragma unroll
            for (int j = 0; j < 8; ++j) {
                pk.s[j] = Smt[(u8 * 8 + j) * 264 + tid_t];
                if constexpr (LAST) msum += bf2f(pk.s[j]);
            }
            *(uint4*)(dst + u8 * 8) = pk.v;
        }
    }
    if constexpr (LAST)
        atomicAdd(&meanb[b * H_DIM + tid_t], msum);
}

// ---------------------------------------------------------------------------
__global__ __launch_bounds__(256) void decode(
    const float* __restrict__ meanb, const float* __restrict__ dw,
    const float* __restrict__ db, float* __restrict__ out)
{
    int i = threadIdx.x;
    if (i >= BATCH * 10) return;
    int b = i / 10, d = i % 10;
    float s = db[d];
    for (int h = 0; h < H_DIM; ++h)
        s = fmaf(meanb[b * H_DIM + h] * (1.f / L_SEQ), dw[d * H_DIM + h], s);
    out[i] = s;
}

// ---------------------------------------------------------------------------
extern "C" void kernel_launch(void* const* d_in, const int* in_sizes, int n_in,
                              void* d_out, int out_size, void* d_ws, size_t ws_size,
                              hipStream_t stream)
{
    const float* x_in = (const float*)d_in[0];
    const float* cw[3] = {(const float*)d_in[1], (const float*)d_in[7],  (const float*)d_in[13]};
    const float* cb[3] = {(const float*)d_in[2], (const float*)d_in[8],  (const float*)d_in[14]};
    const float* bg[3] = {(const float*)d_in[3], (const float*)d_in[9],  (const float*)d_in[15]};
    const float* bb[3] = {(const float*)d_in[4], (const float*)d_in[10], (const float*)d_in[16]};
    const float* bm[3] = {(const float*)d_in[5], (const float*)d_in[11], (const float*)d_in[17]};
    const float* bv[3] = {(const float*)d_in[6], (const float*)d_in[12], (const float*)d_in[18]};
    const float* log_dt   = (const float*)d_in[19];
    const float* A_re_log = (const float*)d_in[20];
    const float* A_im     = (const float*)d_in[21];
    const float* C_re     = (const float*)d_in[22];
    const float* C_im     = (const float*)d_in[23];
    const float* Dv       = (const float*)d_in[24];
    const float* out_w    = (const float*)d_in[25];
    const float* out_b    = (const float*)d_in[26];
    const float* ln_g     = (const float*)d_in[27];
    const float* ln_b     = (const float*)d_in[28];
    const float* dec_w    = (const float*)d_in[29];
    const float* dec_b    = (const float*)d_in[30];

    const size_t PLANE = (size_t)BATCH * H_DIM * L_SEQ;       // 16,777,216 floats
    float* ws = (float*)d_ws;
    unsigned short* xbf = (unsigned short*)ws;                // [B][256][L] bf16
    float* X   = ws + PLANE;            // conv temps -> per-layer matrices
    unsigned short* ybf = (unsigned short*)(ws + 2 * PLANE);  // [B][H][L] bf16
    float* tail = ws + 2 * PLANE + PLANE / 2;
    unsigned short* Wpk = (unsigned short*)tail;              // 1,048,576 us
    float* Ktab  = tail + 524288;                             // (unused, reserved)
    float* wqbuf = Ktab + 32768;
    float* meanb = wqbuf + 32768;
    unsigned short* Wc2 = (unsigned short*)(meanb + 4096);
    float* Bs2 = (float*)(Wc2 + 81920);
    unsigned short* Wc3 = (unsigned short*)(Bs2 + 128);
    float* Bs3 = (float*)(Wc3 + 196608);

    unsigned short* X_us = (unsigned short*)X;
    unsigned short* Vpk = X_us;
    unsigned short* Epk = X_us + 8388608;
    unsigned short* Tpk = X_us + 16777216;

    precompute_wpk<<<256, 256, 0, stream>>>(out_w, Wpk);
    pack_conv<64, 5, 128><<<20, 256, 0, stream>>>(cw[1], bg[1], bv[1], cb[1], bm[1], bb[1], Wc2, Bs2);
    pack_conv<128, 3, 256><<<48, 256, 0, stream>>>(cw[2], bg[2], bv[2], cb[2], bm[2], bb[2], Wc3, Bs3);
    hipMemsetAsync(meanb, 0, BATCH * H_DIM * sizeof(float), stream);

    // Encoder: x_in -> c1p (padded) -> c2p (padded) -> xbf (bf16)
    float* c1p = X;
    float* c2p = X + (size_t)BATCH * 64 * LPAD;
    conv_bn_relu_f<1, 7><<<dim3(16, 2, 16), 256, 0, stream>>>(
        x_in, c1p, cw[0], cb[0], bg[0], bb[0], bm[0], bv[0], 64);
    conv_mfma<64, 5, 128, true, false><<<dim3(128, 16), 256, 0, stream>>>(c1p, c2p, Wc2, Bs2);
    conv_mfma<128, 3, 256, false, true><<<dim3(128, 16), 256, 0, stream>>>(c2p, xbf, Wc3, Bs3);

    for (int l = 0; l < 4; ++l) {
        mats_gen<<<256, 256, 0, stream>>>(log_dt, A_re_log, A_im, C_re, C_im, Dv, l,
                                          Vpk, Epk, Tpk, wqbuf);
        s4d_fused<<<dim3(256, 4), dim3(256), 0, stream>>>(xbf, Vpk, Epk, Tpk, wqbuf, ybf);
        if (l < 3)
            linear_glu_ln<false><<<dim3(64, 16), dim3(512), 0, stream>>>(
                ybf, Wpk + (size_t)l * 262144, out_b + l * 512,
                ln_g + l * H_DIM, ln_b + l * H_DIM, xbf, meanb);
        else
            linear_glu_ln<true><<<dim3(64, 16), dim3(512), 0, stream>>>(
                ybf, Wpk + (size_t)l * 262144, out_b + l * 512,
                ln_g + l * H_DIM, ln_b + l * H_DIM, xbf, meanb);
    }

    decode<<<dim3(1), 256, 0, stream>>>(meanb, dec_w, dec_b, (float*)d_out);
}